// Round 3
// baseline (341.974 us; speedup 1.0000x reference)
//
#include <hip/hip_runtime.h>

typedef _Float16 f16;
typedef _Float16 f16x8 __attribute__((ext_vector_type(8)));
typedef float f32x2 __attribute__((ext_vector_type(2)));
typedef float f32x4 __attribute__((ext_vector_type(4)));
typedef float f32x16 __attribute__((ext_vector_type(16)));
typedef unsigned int u32;
typedef unsigned int u32x4 __attribute__((ext_vector_type(4)));

#define THREADS 512
#define BROWS 256

// d_ws layout (bytes)
#define WS_B1EFF 0                      // 256 f32 (kept for debug)
#define WS_BPERM 1024                   // [5][256] f32: acc-init biases, idx = nt*32 + kh*16 + r
#define WS_W1H   6144                   // [256 n][32 k] f16 (n-major, k<25 valid)  -- NOT swizzled (global reads)
#define WS_W2H   22528                  // [256 n][256 k] f16, XOR-swizzled: idx ^ ((n&7)<<3)
#define WS_W3H   (WS_W2H + 131072)
#define WS_W4H   (WS_W3H + 131072)
#define WS_W5H   (WS_W4H + 131072)      // [32 n][256 k] f16, rows 9..31 zero -- NOT swizzled
#define WS_END   (WS_W5H + 16384)

// R14 prep: weights n-major; W2-4 stored PRE-SWIZZLED so the fused kernel can
// copy them linearly into LDS and read with the same XOR (involution both
// sides, rule: swizzle source+read or neither). bperm = biases permuted into
// the 32x32 C/D row order (n = 32nt + (r&3) + 8(r>>2) + 4kh) for f32x4 acc init.
__global__ void prep_kernel(const float* __restrict__ emb, const int* __restrict__ traj,
                            const float* __restrict__ W1, const float* __restrict__ b1,
                            const float* __restrict__ W2, const float* __restrict__ b2,
                            const float* __restrict__ W3, const float* __restrict__ b3,
                            const float* __restrict__ W4, const float* __restrict__ b4,
                            const float* __restrict__ W5, const float* __restrict__ b5,
                            float* __restrict__ b1eff, float* __restrict__ bperm,
                            f16* __restrict__ W1h, f16* __restrict__ W2h,
                            f16* __restrict__ W3h, f16* __restrict__ W4h,
                            f16* __restrict__ W5h) {
  if (blockIdx.x == 832) {
    __shared__ float lat[128];
    __shared__ float bsh[256];
    int t = *traj;
    if (threadIdx.x < 128) lat[threadIdx.x] = emb[t * 128 + threadIdx.x];
    __syncthreads();
    int n = threadIdx.x;
    float s0 = 0.f, s1 = 0.f, s2 = 0.f, s3 = 0.f;
#pragma unroll 4
    for (int d = 0; d < 128; d += 4) {
      s0 = fmaf(lat[d + 0], W1[(25 + d) * 256 + n], s0);
      s1 = fmaf(lat[d + 1], W1[(26 + d) * 256 + n], s1);
      s2 = fmaf(lat[d + 2], W1[(27 + d) * 256 + n], s2);
      s3 = fmaf(lat[d + 3], W1[(28 + d) * 256 + n], s3);
    }
    float v = b1[n] + ((s0 + s1) + (s2 + s3));
    b1eff[n] = v; bsh[n] = v;
    __syncthreads();
    int i = threadIdx.x;
    int nt = i >> 5, khh = (i >> 4) & 1, r = i & 15;
    int nn = 32 * nt + (r & 3) + 8 * (r >> 2) + 4 * khh;
    bperm[0 * 256 + i] = bsh[nn];
    bperm[1 * 256 + i] = b2[nn];
    bperm[2 * 256 + i] = b3[nn];
    bperm[3 * 256 + i] = b4[nn];
    bperm[4 * 256 + i] = (nn < 9) ? b5[nn] : 0.0f;
    return;
  }
  int i = blockIdx.x * 256 + threadIdx.x;
  if (i < 8192) {
    int n = i >> 5, k = i & 31;
    W1h[i] = (f16)((k < 25) ? W1[k * 256 + n] : 0.0f);
  } else if (i < 73728) {
    int j = i - 8192; int k = j >> 8, n = j & 255;
    W2h[(n * 256 + k) ^ ((n & 7) << 3)] = (f16)W2[j];
  } else if (i < 139264) {
    int j = i - 73728; int k = j >> 8, n = j & 255;
    W3h[(n * 256 + k) ^ ((n & 7) << 3)] = (f16)W3[j];
  } else if (i < 204800) {
    int j = i - 139264; int k = j >> 8, n = j & 255;
    W4h[(n * 256 + k) ^ ((n & 7) << 3)] = (f16)W4[j];
  } else if (i < 212992) {
    int j = i - 204800; int n = j >> 8, k = j & 255;   // n 0..31
    W5h[j] = (f16)((n < 9) ? W5[k * 9 + n] : 0.0f);
  }
}

// Exact-erf GELU on f32x2 (R13-proven: per-element bit-identical to the R11
// scalar chain; backend selects v_pk_fma_f32). DO NOT move to f16 arithmetic
// (R6: 4.6e-4 fail).
__device__ __forceinline__ f32x2 gelu2(f32x2 z) {
  f32x2 s = z * z;
  f32x2 q = __builtin_elementwise_fma(s, (f32x2)(-1.8889263e-5f), (f32x2)(2.30872094e-4f));
  q = __builtin_elementwise_fma(s, q, (f32x2)(-0.0023746714834f));
  q = __builtin_elementwise_fma(s, q, (f32x2)(0.01994711402007f));
  q = __builtin_elementwise_fma(s, q, (f32x2)(-0.13298076013381f));
  q = __builtin_elementwise_fma(s, q, (f32x2)(0.79788456080287f));
  f32x2 t = z * q;
  f32x2 u = 0.5f * z;
  return __builtin_elementwise_fma(u, t, u);
}

__device__ __forceinline__ u32 pack2(float a, float b) {
  unsigned short ha = __builtin_bit_cast(unsigned short, (f16)a);   // RTE, same as R11
  unsigned short hb = __builtin_bit_cast(unsigned short, (f16)b);
  return (u32)ha | ((u32)hb << 16);
}

// GELU + f16-pack + half-wave exchange: converts a 32x32x16 C/D tile
// D[n-rows][m-col=lane&31] into the two B-fragments (k'=32nt..+15, +16..+31)
// of the next layer. Verified against the proven layouts:
//   C/D row = (r&3) + 8(r>>2) + 4kh ;  B elem j = k' = 16kt + 8kh + j.
// Own pairs P[i]=pk(g2i,g2i+1); partner pairs via __shfl_xor(...,32).
__device__ __forceinline__ void exch_pack(const f32x16 acc, int kh, f16x8* fa, f16x8* fb) {
  float g[16];
#pragma unroll
  for (int i = 0; i < 8; ++i) {
    f32x2 r = gelu2((f32x2){acc[2 * i], acc[2 * i + 1]});
    g[2 * i] = r[0]; g[2 * i + 1] = r[1];
  }
  u32 P[8];
#pragma unroll
  for (int i = 0; i < 8; ++i) P[i] = pack2(g[2 * i], g[2 * i + 1]);
  u32 s[8];
#pragma unroll
  for (int i = 0; i < 8; ++i) s[i] = (u32)__shfl_xor((int)P[i], 32);
  u32x4 ua, ub;
  ua[0] = kh ? s[2] : P[0];
  ua[1] = kh ? s[3] : P[1];
  ua[2] = kh ? P[2] : s[0];
  ua[3] = kh ? P[3] : s[1];
  ub[0] = kh ? s[6] : P[4];
  ub[1] = kh ? s[7] : P[5];
  ub[2] = kh ? P[6] : s[4];
  ub[3] = kh ? P[7] : s[5];
  *fa = __builtin_bit_cast(f16x8, ua);
  *fb = __builtin_bit_cast(f16x8, ub);
}

// Copy one 128KB weight matrix (pre-swizzled source) linearly into LDS.
// b128 both sides, lanes contiguous: conflict-free.
__device__ __forceinline__ void stage_w(const f16* __restrict__ src, f16* dst, int tid) {
#pragma unroll
  for (int rdi = 0; rdi < 4; ++rdi) {
    f16x8 t0 = *(const f16x8*)(src + (rdi * 4 + 0) * 4096 + tid * 8);
    f16x8 t1 = *(const f16x8*)(src + (rdi * 4 + 1) * 4096 + tid * 8);
    f16x8 t2 = *(const f16x8*)(src + (rdi * 4 + 2) * 4096 + tid * 8);
    f16x8 t3 = *(const f16x8*)(src + (rdi * 4 + 3) * 4096 + tid * 8);
    *(f16x8*)(dst + (rdi * 4 + 0) * 4096 + tid * 8) = t0;
    *(f16x8*)(dst + (rdi * 4 + 1) * 4096 + tid * 8) = t1;
    *(f16x8*)(dst + (rdi * 4 + 2) * 4096 + tid * 8) = t2;
    *(f16x8*)(dst + (rdi * 4 + 3) * 4096 + tid * 8) = t3;
  }
}

// R14: register-resident activations (swapped-operand MFMA, D = W^T X^T).
// - wave owns 32 batch rows; lane pair (c, kh=0/1) holds row 32w+c's full
//   feature vector as B-frags (16 x f16x8). No activation LDS traffic, no
//   intra-layer barriers (5 syncthreads total vs ~12).
// - A = weights: W1/W5 read from global (L2-hot); W2-4 staged per layer into
//   LDS (131KB, 1 block/CU), XOR-swizzled -> b128 reads at the 4-way BW floor.
// - Chains share B (proven-safe); A-frags fresh per chain (the banned
//   A-register sharing pattern never occurs).
// - L2-4 accumulation order bitwise-identical to R11/R13 (bias-first,
//   ascending k, same MFMA instr). L1/L5 regrouped 16x16x32 -> 2/16x 32x32x16.
__global__ __launch_bounds__(THREADS, 2) void fused_kernel(
    const float* __restrict__ Fg, const float* __restrict__ Cg,
    const f16* __restrict__ W1h, const f16* __restrict__ W2h,
    const f16* __restrict__ W3h, const f16* __restrict__ W4h,
    const f16* __restrict__ W5h, const float* __restrict__ bperm,
    float* __restrict__ outg, int Btot) {
  __shared__ __align__(16) f16 Wlds[65536];   // 131072 B

  const int tid = threadIdx.x;
  const int lane = tid & 63;
  const int wv = tid >> 6;          // 0..7
  const int l31 = lane & 31;
  const int kh = lane >> 5;         // 0/1
  const int myrow = blockIdx.x * BROWS + wv * 32 + l31;   // both kh halves: same row

  // ---- stage W2 (issue early; consumed after the L2 barrier) ----
  stage_w(W2h, Wlds, tid);

  // ---- phase A: per-row strain features + polar rotation (all 512 threads;
  //      the two kh halves duplicate the same row -> no exchange needed) ----
  float feat[25];
  float Rm[9];
  if (myrow < Btot) {
    float Fm[9], Cm[9];
    const float* fp = Fg + myrow * 9;
    const float* cp = Cg + myrow * 9;
#pragma unroll
    for (int i = 0; i < 9; ++i) Fm[i] = fp[i];
#pragma unroll
    for (int i = 0; i < 9; ++i) Cm[i] = cp[i];
    float G[9];  // F^T F
#pragma unroll
    for (int i = 0; i < 3; ++i)
#pragma unroll
      for (int j = 0; j < 3; ++j)
        G[i * 3 + j] = Fm[i] * Fm[j] + Fm[3 + i] * Fm[3 + j] + Fm[6 + i] * Fm[6 + j];
    float det = Fm[0] * (Fm[4] * Fm[8] - Fm[5] * Fm[7])
              - Fm[1] * (Fm[3] * Fm[8] - Fm[5] * Fm[6])
              + Fm[2] * (Fm[3] * Fm[7] - Fm[4] * Fm[6]);
#pragma unroll
    for (int i = 0; i < 9; ++i) Rm[i] = Fm[i];
#pragma unroll
    for (int it = 0; it < 5; ++it) {
      float c0 = Rm[4]*Rm[8] - Rm[5]*Rm[7];
      float c1 = Rm[5]*Rm[6] - Rm[3]*Rm[8];
      float c2 = Rm[3]*Rm[7] - Rm[4]*Rm[6];
      float c3 = Rm[2]*Rm[7] - Rm[1]*Rm[8];
      float c4 = Rm[0]*Rm[8] - Rm[2]*Rm[6];
      float c5 = Rm[1]*Rm[6] - Rm[0]*Rm[7];
      float c6 = Rm[1]*Rm[5] - Rm[2]*Rm[4];
      float c7 = Rm[2]*Rm[3] - Rm[0]*Rm[5];
      float c8 = Rm[0]*Rm[4] - Rm[1]*Rm[3];
      float dr = Rm[0]*c0 + Rm[1]*c1 + Rm[2]*c2;
      float hv = 0.5f / dr;
      Rm[0] = 0.5f*Rm[0] + hv*c0; Rm[1] = 0.5f*Rm[1] + hv*c1; Rm[2] = 0.5f*Rm[2] + hv*c2;
      Rm[3] = 0.5f*Rm[3] + hv*c3; Rm[4] = 0.5f*Rm[4] + hv*c4; Rm[5] = 0.5f*Rm[5] + hv*c5;
      Rm[6] = 0.5f*Rm[6] + hv*c6; Rm[7] = 0.5f*Rm[7] + hv*c7; Rm[8] = 0.5f*Rm[8] + hv*c8;
    }
    float s00 = Rm[0]*Fm[0] + Rm[3]*Fm[3] + Rm[6]*Fm[6];
    float s11 = Rm[1]*Fm[1] + Rm[4]*Fm[4] + Rm[7]*Fm[7];
    float s22 = Rm[2]*Fm[2] + Rm[5]*Fm[5] + Rm[8]*Fm[8];
    float s01 = 0.5f*((Rm[0]*Fm[1]+Rm[3]*Fm[4]+Rm[6]*Fm[7]) + (Rm[1]*Fm[0]+Rm[4]*Fm[3]+Rm[7]*Fm[6]));
    float s02 = 0.5f*((Rm[0]*Fm[2]+Rm[3]*Fm[5]+Rm[6]*Fm[8]) + (Rm[2]*Fm[0]+Rm[5]*Fm[3]+Rm[8]*Fm[6]));
    float s12 = 0.5f*((Rm[1]*Fm[2]+Rm[4]*Fm[5]+Rm[7]*Fm[8]) + (Rm[2]*Fm[1]+Rm[5]*Fm[4]+Rm[8]*Fm[7]));
    float q  = (s00 + s11 + s22) * (1.0f/3.0f);
    float p1 = s01*s01 + s02*s02 + s12*s12;
    float d0 = s00 - q, d1 = s11 - q, d2 = s22 - q;
    float p2 = d0*d0 + d1*d1 + d2*d2 + 2.0f*p1;
    float p  = sqrtf(p2 * (1.0f/6.0f));
    float e1, e2, e3;
    if (p > 1e-10f) {
      float pi = 1.0f / p;
      float b00 = d0*pi, b11 = d1*pi, b22 = d2*pi;
      float b01 = s01*pi, b02 = s02*pi, b12 = s12*pi;
      float detB = b00*(b11*b22 - b12*b12) - b01*(b01*b22 - b12*b02) + b02*(b01*b12 - b11*b02);
      float r = fminf(fmaxf(0.5f*detB, -1.0f), 1.0f);
      float phi = acosf(r) * (1.0f/3.0f);
      e1 = q + 2.0f * p * cosf(phi);
      e3 = q + 2.0f * p * cosf(phi + 2.0943951023931953f);
      e2 = 3.0f*q - e1 - e3;
    } else { e1 = q; e2 = q; e3 = q; }
    float f00 = fmaxf(Fm[0], 1e-6f);
    feat[0] = e1 - 1.0f; feat[1] = e2 - 1.0f; feat[2] = e3 - 1.0f;
#pragma unroll
    for (int k = 0; k < 9; ++k) feat[3 + k] = G[k];
    feat[3] -= 1.0f; feat[7] -= 1.0f; feat[11] -= 1.0f;
    feat[12] = det - 1.0f;
    feat[13] = logf(det) - 1.0f;
    feat[14] = f00 - 1.0f;
    feat[15] = logf(f00) - 1.0f;
#pragma unroll
    for (int k = 0; k < 9; ++k) feat[16 + k] = Cm[k];
  } else {
#pragma unroll
    for (int k = 0; k < 25; ++k) feat[k] = 0.0f;
#pragma unroll
    for (int k = 0; k < 9; ++k) Rm[k] = 0.0f;
  }

  // ---- build X1 B-frags (K=32: kt0 = feats 0..15, kt1 = 16..31, pad>=25) ----
  f16x8 xa, xb;
#pragma unroll
  for (int j = 0; j < 8; ++j) xa[j] = (f16)(kh ? feat[8 + j] : feat[j]);
#pragma unroll
  for (int j = 0; j < 8; ++j) {
    int k = 16 + 8 * kh + j;
    xb[j] = (f16)((k < 25) ? feat[k] : 0.0f);
  }

  // ---- L1: W1 (global, [n][32]) x X1 -> X2 frags ----
  f16x8 X[16];
  {
    const float* bp = bperm + 0 * 256 + kh * 16;
#pragma unroll
    for (int nt = 0; nt < 8; ++nt) {
      const f32x4* bq = (const f32x4*)(bp + nt * 32);
      f32x4 c0 = bq[0], c1 = bq[1], c2 = bq[2], c3 = bq[3];
      f32x16 acc;
#pragma unroll
      for (int r = 0; r < 4; ++r) { acc[r] = c0[r]; acc[4 + r] = c1[r]; acc[8 + r] = c2[r]; acc[12 + r] = c3[r]; }
      const f16* wb = W1h + (nt * 32 + l31) * 32 + kh * 8;
      f16x8 w0 = *(const f16x8*)(wb);
      f16x8 w1 = *(const f16x8*)(wb + 16);
      acc = __builtin_amdgcn_mfma_f32_32x32x16_f16(w0, xa, acc, 0, 0, 0);
      acc = __builtin_amdgcn_mfma_f32_32x32x16_f16(w1, xb, acc, 0, 0, 0);
      exch_pack(acc, kh, &X[2 * nt], &X[2 * nt + 1]);
    }
  }

  // ---- hidden layers 2..4: A = staged W (LDS, swizzled), B = X frags ----
#pragma unroll 1
  for (int L = 0; L < 3; ++L) {
    if (L > 0) {
      __syncthreads();                         // everyone done reading Wlds
      stage_w((L == 1) ? W3h : W4h, Wlds, tid);
    }
    __syncthreads();                           // staged weights visible
    const float* bp = bperm + (L + 1) * 256 + kh * 16;
    f16x8 Xn[16];
#pragma unroll
    for (int nt = 0; nt < 8; ++nt) {
      const f32x4* bq = (const f32x4*)(bp + nt * 32);
      f32x4 c0 = bq[0], c1 = bq[1], c2 = bq[2], c3 = bq[3];
      f32x16 acc;
#pragma unroll
      for (int r = 0; r < 4; ++r) { acc[r] = c0[r]; acc[4 + r] = c1[r]; acc[8 + r] = c2[r]; acc[12 + r] = c3[r]; }
#pragma unroll
      for (int kt = 0; kt < 16; ++kt) {
        const int a = ((nt * 32 + l31) * 256 + kt * 16 + kh * 8) ^ ((l31 & 7) << 3);
        f16x8 w = *(const f16x8*)(Wlds + a);
        acc = __builtin_amdgcn_mfma_f32_32x32x16_f16(w, X[kt], acc, 0, 0, 0);
      }
      exch_pack(acc, kh, &Xn[2 * nt], &Xn[2 * nt + 1]);
    }
#pragma unroll
    for (int t2 = 0; t2 < 16; ++t2) X[t2] = Xn[t2];
  }

  // ---- L5: W5 (global, [32][256], rows>=9 zero) x X5; n-tile 0 only ----
  f32x16 acc5;
  {
    const float* bp = bperm + 4 * 256 + kh * 16;
    const f32x4* bq = (const f32x4*)(bp);
    f32x4 c0 = bq[0], c1 = bq[1], c2 = bq[2], c3 = bq[3];
#pragma unroll
    for (int r = 0; r < 4; ++r) { acc5[r] = c0[r]; acc5[4 + r] = c1[r]; acc5[8 + r] = c2[r]; acc5[12 + r] = c3[r]; }
#pragma unroll
    for (int kt = 0; kt < 16; ++kt) {
      f16x8 w = *(const f16x8*)(W5h + l31 * 256 + kt * 16 + kh * 8);
      acc5 = __builtin_amdgcn_mfma_f32_32x32x16_f16(w, X[kt], acc5, 0, 0, 0);
    }
  }

  // ---- final: gather out[0..8] to kh=0 lanes, cauchy = R sym(x) F^T ----
  // kh=0 rows r0-3 -> n0-3, r4 -> n8 ; partner (kh=1) r0-3 -> n4-7.
  float sx0 = __shfl_xor(acc5[0], 32);
  float sx1 = __shfl_xor(acc5[1], 32);
  float sx2 = __shfl_xor(acc5[2], 32);
  float sx3 = __shfl_xor(acc5[3], 32);
  if (kh == 0 && myrow < Btot) {
    float x[9];
    x[0] = acc5[0]; x[1] = acc5[1]; x[2] = acc5[2]; x[3] = acc5[3];
    x[4] = sx0; x[5] = sx1; x[6] = sx2; x[7] = sx3;
    x[8] = acc5[4];
    const float* fp = Fg + myrow * 9;
    float Fm[9];
#pragma unroll
    for (int i = 0; i < 9; ++i) Fm[i] = fp[i];
    float y[9];
    y[0] = x[0]; y[4] = x[4]; y[8] = x[8];
    y[1] = 0.5f * (x[1] + x[3]); y[3] = y[1];
    y[2] = 0.5f * (x[2] + x[6]); y[6] = y[2];
    y[5] = 0.5f * (x[5] + x[7]); y[7] = y[5];
    float P[9];
#pragma unroll
    for (int i = 0; i < 3; ++i)
#pragma unroll
      for (int j = 0; j < 3; ++j)
        P[i*3+j] = Rm[i*3]*y[j] + Rm[i*3+1]*y[3+j] + Rm[i*3+2]*y[6+j];
#pragma unroll
    for (int i = 0; i < 3; ++i)
#pragma unroll
      for (int j = 0; j < 3; ++j)
        outg[myrow * 9 + i*3 + j] = P[i*3]*Fm[j*3] + P[i*3+1]*Fm[j*3+1] + P[i*3+2]*Fm[j*3+2];
  }
}

extern "C" void kernel_launch(void* const* d_in, const int* in_sizes, int n_in,
                              void* d_out, int out_size, void* d_ws, size_t ws_size,
                              hipStream_t stream) {
  const float* Fg  = (const float*)d_in[0];
  const float* Cg  = (const float*)d_in[1];
  const float* emb = (const float*)d_in[2];
  const int*   trj = (const int*)d_in[3];
  const float* W1  = (const float*)d_in[4];
  const float* b1  = (const float*)d_in[5];
  const float* W2  = (const float*)d_in[6];
  const float* b2  = (const float*)d_in[7];
  const float* W3  = (const float*)d_in[8];
  const float* b3  = (const float*)d_in[9];
  const float* W4  = (const float*)d_in[10];
  const float* b4  = (const float*)d_in[11];
  const float* W5  = (const float*)d_in[12];
  const float* b5  = (const float*)d_in[13];
  float* outg = (float*)d_out;
  const int Btot = in_sizes[0] / 9;

  char* ws = (char*)d_ws;
  float* b1eff = (float*)(ws + WS_B1EFF);
  float* bperm = (float*)(ws + WS_BPERM);
  f16* W1h = (f16*)(ws + WS_W1H);
  f16* W2h = (f16*)(ws + WS_W2H);
  f16* W3h = (f16*)(ws + WS_W3H);
  f16* W4h = (f16*)(ws + WS_W4H);
  f16* W5h = (f16*)(ws + WS_W5H);

  prep_kernel<<<833, 256, 0, stream>>>(emb, trj, W1, b1, W2, b2, W3, b3, W4, b4,
                                       W5, b5, b1eff, bperm,
                                       W1h, W2h, W3h, W4h, W5h);
  const int grid = (Btot + BROWS - 1) / BROWS;
  fused_kernel<<<grid, THREADS, 0, stream>>>(Fg, Cg, W1h, W2h, W3h, W4h, W5h,
                                             bperm, outg, Btot);
}